// Round 3
// baseline (160.874 us; speedup 1.0000x reference)
//
#include <hip/hip_runtime.h>

// out[b,v] = dot(OT[b, pid[v], :], W[v, :]) + bias[v]
// B=32, Q=180, H=768, V=19004. All fp32.
#define BB 32
#define QQ 180
#define HH 768
#define VV 19004
#define VB 64
#define HK 32
#define NTMAX 480
#define SB 19008   // res stride in pos dim

// ws layout (bytes)
#define WS_CNT    0        // 256 ints
#define WS_CUR    1024     // 256 ints
#define WS_NTOT   2048     // 1 int
#define WS_SORTED 4096     // VV ints (76016 -> reserve 76800)
#define WS_POSOF  80896    // VV ints (reserve 76800)
#define WS_DESC   157696   // 480 int4 (reserve 8192)
#define WS_RES    165888   // nsplit * 32 * 19008 floats

// ---------- pre-pass ----------
__global__ void count_k(const int* __restrict__ pid, int* __restrict__ cnt) {
    __shared__ int lc[QQ];
    for (int i = threadIdx.x; i < QQ; i += blockDim.x) lc[i] = 0;
    __syncthreads();
    for (int v = blockIdx.x * blockDim.x + threadIdx.x; v < VV;
         v += gridDim.x * blockDim.x)
        atomicAdd(&lc[pid[v]], 1);
    __syncthreads();
    for (int i = threadIdx.x; i < QQ; i += blockDim.x) {
        int c = lc[i];
        if (c) atomicAdd(&cnt[i], c);
    }
}

__global__ void scan_desc_k(const int* __restrict__ cnt, int* __restrict__ cursor,
                            int4* __restrict__ desc, int* __restrict__ ntot) {
    __shared__ int sc[256];
    __shared__ int sn[256];
    const int t = threadIdx.x;
    const int c = (t < QQ) ? cnt[t] : 0;
    sc[t] = c;
    __syncthreads();
    for (int off = 1; off < 256; off <<= 1) {
        int add = (t >= off) ? sc[t - off] : 0;
        __syncthreads();
        sc[t] += add;
        __syncthreads();
    }
    const int qstart = sc[t] - c;
    if (t < QQ) cursor[t] = qstart;
    const int nch = (c + VB - 1) / VB;
    sn[t] = nch;
    __syncthreads();
    for (int off = 1; off < 256; off <<= 1) {
        int add = (t >= off) ? sn[t - off] : 0;
        __syncthreads();
        sn[t] += add;
        __syncthreads();
    }
    const int cb = sn[t] - nch;
    if (t < QQ) {
        for (int j = 0; j < nch; ++j)
            desc[cb + j] = make_int4(t, qstart + j * VB, min(VB, c - j * VB), 0);
    }
    if (t == 255) *ntot = sn[255];
}

__global__ void scatter_k(const int* __restrict__ pid, int* __restrict__ cursor,
                          int* __restrict__ sorted, int* __restrict__ posOf) {
    for (int v = blockIdx.x * blockDim.x + threadIdx.x; v < VV;
         v += gridDim.x * blockDim.x) {
        int q = pid[v];
        int pos = atomicAdd(&cursor[q], 1);
        sorted[pos] = v;
        posOf[v] = pos;
    }
}

// ---------- main: 1-wave blocks, 64v x 32b tile, 8v x 4b per-thread ----------
// t = u + 8g (u=t&7, g=t>>3). Thread owns v-locals {8u..8u+7}, b's {4g..4g+3}.
// LDS swizzle: logical (row, col4) stored at col4 ^ f(row); W: f=(r>>3)^(r&7),
// OT: f=(r>>2). All operand reads are 8-unique-address x broadcast-8,
// conflict-free (banks 4*(distinct mod 8)).
__launch_bounds__(64, 3)
__global__ void main_k(const float* __restrict__ OT, const float* __restrict__ W,
                       const int* __restrict__ sorted, const int4* __restrict__ desc,
                       const int* __restrict__ ntot, float* __restrict__ res,
                       int nsplit, int lsplit, int nc) {
    const int nt = *ntot;
    const int bid = blockIdx.x;
    if (bid >= (nt << lsplit)) return;
    const int ci = bid >> lsplit;
    const int s = bid & (nsplit - 1);
    const int4 d = desc[ci];
    const int q = d.x, start = d.y, len = d.z;
    const int h0 = s * (nc * HK);

    __shared__ float Wt[VB * HK];  // 8 KB
    __shared__ float Tt[BB * HK];  // 4 KB
    __shared__ int svs[VB];

    const int t = threadIdx.x;
    const int u = t & 7;
    const int g = t >> 3;
    svs[t] = sorted[start + min(t, len - 1)];
    __syncthreads();

    const float* wb[8];
#pragma unroll
    for (int p = 0; p < 8; ++p)
        wb[p] = W + (size_t)svs[8 * p + g] * HH + h0 + u * 4;
    const float* ob[4];
#pragma unroll
    for (int p = 0; p < 4; ++p)
        ob[p] = OT + ((size_t)(8 * p + g) * QQ + q) * HH + h0 + u * 4;

    float4 wr[8], orr[4];
#pragma unroll
    for (int p = 0; p < 8; ++p) wr[p] = *(const float4*)(wb[p]);
#pragma unroll
    for (int p = 0; p < 4; ++p) orr[p] = *(const float4*)(ob[p]);

    float acc[8][4];
#pragma unroll
    for (int i = 0; i < 8; ++i)
#pragma unroll
        for (int j = 0; j < 4; ++j) acc[i][j] = 0.f;

    for (int c = 0; c < nc; ++c) {
        __syncthreads();
#pragma unroll
        for (int p = 0; p < 8; ++p)
            *(float4*)&Wt[(8 * p + g) * HK + (((u ^ p ^ g) & 7) << 2)] = wr[p];
#pragma unroll
        for (int p = 0; p < 4; ++p) {
            const int r = 8 * p + g;
            *(float4*)&Tt[r * HK + (((u ^ (r >> 2)) & 7) << 2)] = orr[p];
        }
        __syncthreads();
        if (c + 1 < nc) {
            const int off = (c + 1) * HK;
#pragma unroll
            for (int p = 0; p < 8; ++p) wr[p] = *(const float4*)(wb[p] + off);
#pragma unroll
            for (int p = 0; p < 4; ++p) orr[p] = *(const float4*)(ob[p] + off);
        }
#pragma unroll
        for (int sc = 0; sc < 8; ++sc) {
            float4 wv[8], ov[4];
#pragma unroll
            for (int i = 0; i < 8; ++i)
                wv[i] = *(const float4*)&Wt[(8 * u + i) * HK + (((sc ^ u ^ i) & 7) << 2)];
#pragma unroll
            for (int j = 0; j < 4; ++j)
                ov[j] = *(const float4*)&Tt[(4 * g + j) * HK + (((sc ^ g) & 7) << 2)];
#pragma unroll
            for (int i = 0; i < 8; ++i)
#pragma unroll
                for (int j = 0; j < 4; ++j) {
                    acc[i][j] = fmaf(wv[i].x, ov[j].x, acc[i][j]);
                    acc[i][j] = fmaf(wv[i].y, ov[j].y, acc[i][j]);
                    acc[i][j] = fmaf(wv[i].z, ov[j].z, acc[i][j]);
                    acc[i][j] = fmaf(wv[i].w, ov[j].w, acc[i][j]);
                }
        }
    }

    // compact store: res[s][b][start + 8u + i]
    const int vbase = 8 * u;
#pragma unroll
    for (int j = 0; j < 4; ++j) {
        const int b = 4 * g + j;
        float* outp = res + ((size_t)(s * BB + b)) * SB + start + vbase;
        if (vbase + 7 < len) {
#pragma unroll
            for (int i = 0; i < 8; ++i) outp[i] = acc[i][j];
        } else {
#pragma unroll
            for (int i = 0; i < 8; ++i)
                if (vbase + i < len) outp[i] = acc[i][j];
        }
    }
}

// ---------- combine: coalesced out-writes, gathered res reads ----------
__global__ void combine_k(const float* __restrict__ res, const int* __restrict__ posOf,
                          const float* __restrict__ bias, float* __restrict__ out,
                          int nsplit) {
    const int v = blockIdx.x * 256 + threadIdx.x;
    if (v >= VV) return;
    const int b = blockIdx.y;
    const int pos = posOf[v];
    float a = bias[v];
    for (int s = 0; s < nsplit; ++s)
        a += res[((size_t)(s * BB + b)) * SB + pos];
    out[(size_t)b * VV + v] = a;
}

extern "C" void kernel_launch(void* const* d_in, const int* in_sizes, int n_in,
                              void* d_out, int out_size, void* d_ws, size_t ws_size,
                              hipStream_t stream) {
    const float* OT   = (const float*)d_in[0];  // [B,Q,H]
    const float* W    = (const float*)d_in[1];  // [V,H]
    const float* bias = (const float*)d_in[2];  // [V]
    const int*   pid  = (const int*)d_in[3];    // [V]
    float* out = (float*)d_out;                 // [B,V]

    char* ws = (char*)d_ws;
    int*   cnt    = (int*)(ws + WS_CNT);
    int*   cursor = (int*)(ws + WS_CUR);
    int*   ntot   = (int*)(ws + WS_NTOT);
    int*   sorted = (int*)(ws + WS_SORTED);
    int*   posOf  = (int*)(ws + WS_POSOF);
    int4*  desc   = (int4*)(ws + WS_DESC);
    float* res    = (float*)(ws + WS_RES);

    const size_t resbytes1 = (size_t)BB * SB * 4;  // per split: 2.433 MB
    int nsplit, lsplit;
    if      (ws_size >= WS_RES + 8 * resbytes1) { nsplit = 8; lsplit = 3; }
    else if (ws_size >= WS_RES + 4 * resbytes1) { nsplit = 4; lsplit = 2; }
    else if (ws_size >= WS_RES + 2 * resbytes1) { nsplit = 2; lsplit = 1; }
    else                                        { nsplit = 1; lsplit = 0; }
    const int nc = (HH / nsplit) / HK;

    hipMemsetAsync(cnt, 0, 256 * sizeof(int), stream);
    count_k<<<80, 256, 0, stream>>>(pid, cnt);
    scan_desc_k<<<1, 256, 0, stream>>>(cnt, cursor, desc, ntot);
    scatter_k<<<80, 256, 0, stream>>>(pid, cursor, sorted, posOf);

    main_k<<<NTMAX * nsplit, 64, 0, stream>>>(OT, W, sorted, desc, ntot, res,
                                              nsplit, lsplit, nc);

    combine_k<<<dim3((VV + 255) / 256, BB), 256, 0, stream>>>(res, posOf, bias,
                                                              out, nsplit);
}

// Round 4
// 80.732 us; speedup vs baseline: 1.9927x; 1.9927x over previous
//
#include <hip/hip_runtime.h>

// out[b,v] = dot(OT[b, pid[v], :], W[v, :]) + bias[v]
// B=32, Q=180, H=768, V=19004. All fp32.
#define BB 32
#define QQ 180
#define HH 768
#define VV 19004
#define VB 64
#define HQ 192      // h per quarter
#define SB 19008    // res stride (pos dim)
#define MAXDESC 480

// ws layout (bytes)
#define WS_CNT    0        // 256 ints
#define WS_CUR    1024     // 256 ints
#define WS_NTOT   2048     // 1 int
#define WS_SORTED 4096     // VV ints (76016 B)
#define WS_DESC   81920    // 480 int4 (7680 B)
#define WS_RES    90112    // 4 * 32 * 19008 * 4 = 9,732,096 B

// ---------- pre-pass ----------
__global__ void count_k(const int* __restrict__ pid, int* __restrict__ cnt) {
    __shared__ int lc[QQ];
    for (int i = threadIdx.x; i < QQ; i += blockDim.x) lc[i] = 0;
    __syncthreads();
    for (int v = blockIdx.x * blockDim.x + threadIdx.x; v < VV;
         v += gridDim.x * blockDim.x)
        atomicAdd(&lc[pid[v]], 1);
    __syncthreads();
    for (int i = threadIdx.x; i < QQ; i += blockDim.x) {
        int c = lc[i];
        if (c) atomicAdd(&cnt[i], c);
    }
}

__global__ void scan_desc_k(const int* __restrict__ cnt, int* __restrict__ cursor,
                            int4* __restrict__ desc, int* __restrict__ ntot) {
    __shared__ int sc[256];
    __shared__ int sn[256];
    const int t = threadIdx.x;
    const int c = (t < QQ) ? cnt[t] : 0;
    sc[t] = c;
    __syncthreads();
    for (int off = 1; off < 256; off <<= 1) {
        int add = (t >= off) ? sc[t - off] : 0;
        __syncthreads();
        sc[t] += add;
        __syncthreads();
    }
    const int qstart = sc[t] - c;
    if (t < QQ) cursor[t] = qstart;
    const int nch = (c + VB - 1) / VB;
    sn[t] = nch;
    __syncthreads();
    for (int off = 1; off < 256; off <<= 1) {
        int add = (t >= off) ? sn[t - off] : 0;
        __syncthreads();
        sn[t] += add;
        __syncthreads();
    }
    const int cb = sn[t] - nch;
    if (t < QQ) {
        for (int j = 0; j < nch; ++j)
            desc[cb + j] = make_int4(t, qstart + j * VB, min(VB, c - j * VB), 0);
    }
    if (t == 255) *ntot = sn[255];
}

__global__ void scatter_k(const int* __restrict__ pid, int* __restrict__ cursor,
                          int* __restrict__ sorted) {
    for (int v = blockIdx.x * blockDim.x + threadIdx.x; v < VV;
         v += gridDim.x * blockDim.x) {
        int q = pid[v];
        int pos = atomicAdd(&cursor[q], 1);
        sorted[pos] = v;
    }
}

// ---------- main: lane=v, wave=8b (OT via SGPR), block=h-quarter ----------
// block bid: chunk ci = bid>>2, h-quarter hq = bid&3. 256 thr = 4 waves.
// Wave w handles b = 8w..8w+7. Lane = v-slot (64 v per chunk).
// OT[b,q,h] is wave-uniform -> scalar loads; inner loop = v_fmac(s_ot, v_w).
// W[v,:] per-lane from global (L1 serves the x4 bgroup reuse, regs the x8 b).
// No LDS, no shuffles. res stores: 64 consecutive dwords per wave per b.
__launch_bounds__(256)
__global__ void main_k(const float* __restrict__ OT, const float* __restrict__ W,
                       const int* __restrict__ sorted, const int4* __restrict__ desc,
                       const int* __restrict__ ntot, float* __restrict__ res) {
    const int nt = *ntot;
    const int bid = blockIdx.x;
    const int ci = bid >> 2;
    if (ci >= nt) return;
    const int hq = bid & 3;
    const int4 d = desc[ci];
    const int q     = __builtin_amdgcn_readfirstlane(d.x);
    const int start = __builtin_amdgcn_readfirstlane(d.y);
    const int len   = __builtin_amdgcn_readfirstlane(d.z);
    const int lane = threadIdx.x & 63;
    const int w = __builtin_amdgcn_readfirstlane(threadIdx.x >> 6);

    const int v = sorted[start + min(lane, len - 1)];
    const float* wp = W + (size_t)v * HH + hq * HQ;

    const float* ob[8];
#pragma unroll
    for (int j = 0; j < 8; ++j)
        ob[j] = OT + ((size_t)(8 * w + j) * QQ + q) * HH + hq * HQ;

    float acc[8] = {0.f, 0.f, 0.f, 0.f, 0.f, 0.f, 0.f, 0.f};

#pragma unroll 4
    for (int t = 0; t < HQ / 4; ++t) {
        const float4 wr = *(const float4*)(wp + 4 * t);
#pragma unroll
        for (int j = 0; j < 8; ++j) {
            const float* o = ob[j] + 4 * t;
            float a = acc[j];
            a = fmaf(wr.x, o[0], a);
            a = fmaf(wr.y, o[1], a);
            a = fmaf(wr.z, o[2], a);
            a = fmaf(wr.w, o[3], a);
            acc[j] = a;
        }
    }

    if (lane < len) {
        float* rp = res + (size_t)(hq * BB + 8 * w) * SB + start + lane;
#pragma unroll
        for (int j = 0; j < 8; ++j)
            rp[(size_t)j * SB] = acc[j];
    }
}

// ---------- combine in pos-space: all reads coalesced ----------
__global__ void combine_k(const float* __restrict__ res, const int* __restrict__ sorted,
                          const float* __restrict__ bias, float* __restrict__ out) {
    const int pos = blockIdx.x * 256 + threadIdx.x;
    if (pos >= VV) return;
    const int b = blockIdx.y;
    float s = res[(size_t)b * SB + pos]
            + res[(size_t)(BB + b) * SB + pos]
            + res[(size_t)(2 * BB + b) * SB + pos]
            + res[(size_t)(3 * BB + b) * SB + pos];
    const int v = sorted[pos];
    out[(size_t)b * VV + v] = s + bias[v];
}

extern "C" void kernel_launch(void* const* d_in, const int* in_sizes, int n_in,
                              void* d_out, int out_size, void* d_ws, size_t ws_size,
                              hipStream_t stream) {
    const float* OT   = (const float*)d_in[0];  // [B,Q,H]
    const float* W    = (const float*)d_in[1];  // [V,H]
    const float* bias = (const float*)d_in[2];  // [V]
    const int*   pid  = (const int*)d_in[3];    // [V]
    float* out = (float*)d_out;                 // [B,V]

    char* ws = (char*)d_ws;
    int*   cnt    = (int*)(ws + WS_CNT);
    int*   cursor = (int*)(ws + WS_CUR);
    int*   ntot   = (int*)(ws + WS_NTOT);
    int*   sorted = (int*)(ws + WS_SORTED);
    int4*  desc   = (int4*)(ws + WS_DESC);
    float* res    = (float*)(ws + WS_RES);

    hipMemsetAsync(cnt, 0, 256 * sizeof(int), stream);
    count_k<<<80, 256, 0, stream>>>(pid, cnt);
    scan_desc_k<<<1, 256, 0, stream>>>(cnt, cursor, desc, ntot);
    scatter_k<<<80, 256, 0, stream>>>(pid, cursor, sorted);

    main_k<<<4 * MAXDESC, 256, 0, stream>>>(OT, W, sorted, desc, ntot, res);

    combine_k<<<dim3((VV + 255) / 256, BB), 256, 0, stream>>>(res, sorted, bias, out);
}

// Round 5
// 76.100 us; speedup vs baseline: 2.1140x; 1.0609x over previous
//
#include <hip/hip_runtime.h>

// out[b,v] = dot(OT[b, pid[v], :], W[v, :]) + bias[v]
// B=32, Q=180, H=768, V=19004. All fp32.
#define BB 32
#define QQ 180
#define HH 768
#define VV 19004
#define VB 64
#define HQ 192      // h per quarter
#define SB 19008    // res stride (pos dim)
#define MAXDESC 480

// ws layout (bytes)
#define WS_NTOT   2048     // 1 int
#define WS_SORTED 4096     // VV ints (76016 B)
#define WS_DESC   81920    // 480 int4 (7680 B)
#define WS_RES    90112    // 4 * 32 * 19008 * 4 = 9,732,096 B

// ---------- fused pre-pass: histogram + scan + desc + scatter, 1 block ----------
__global__ void prep_k(const int* __restrict__ pid, int* __restrict__ sorted,
                       int4* __restrict__ desc, int* __restrict__ ntot) {
    __shared__ int cnt[256];
    __shared__ int sc[256];
    __shared__ int sn[256];
    __shared__ int cur[256];
    const int t = threadIdx.x;  // 1024 threads
    if (t < 256) cnt[t] = 0;
    __syncthreads();
    for (int v = t; v < VV; v += 1024) atomicAdd(&cnt[pid[v]], 1);
    __syncthreads();
    if (t < 256) sc[t] = cnt[t];
    __syncthreads();
    for (int off = 1; off < 256; off <<= 1) {
        int add = (t < 256 && t >= off) ? sc[t - off] : 0;
        __syncthreads();
        if (t < 256) sc[t] += add;
        __syncthreads();
    }
    // sc = inclusive prefix of cnt
    if (t < 256) {
        const int c = cnt[t];
        cur[t] = sc[t] - c;                      // q start
        sn[t] = (c + VB - 1) / VB;               // chunks for this q
    }
    __syncthreads();
    for (int off = 1; off < 256; off <<= 1) {
        int add = (t < 256 && t >= off) ? sn[t - off] : 0;
        __syncthreads();
        if (t < 256) sn[t] += add;
        __syncthreads();
    }
    if (t < QQ) {
        const int c = cnt[t];
        const int nch = (c + VB - 1) / VB;
        const int cb = sn[t] - nch;
        const int qs = cur[t];
        for (int j = 0; j < nch; ++j)
            desc[cb + j] = make_int4(t, qs + j * VB, min(VB, c - j * VB), 0);
    }
    if (t == 255) *ntot = sn[255];
    __syncthreads();
    for (int v = t; v < VV; v += 1024) {
        const int q = pid[v];
        const int pos = atomicAdd(&cur[q], 1);   // LDS atomic: fast
        sorted[pos] = v;
    }
}

// ---------- main: lane=v, wave=8b, OT broadcast from LDS ----------
// bid: chunk ci = bid>>2, h-quarter hq = bid&3. 256 thr = 4 waves.
// Wave w: b = 8w..8w+7. Lane = v-slot. OT quarter (32b x 192h = 24 KB) staged
// in LDS once; inner loop reads it via wave-uniform ds_read_b128 (broadcast,
// conflict-free, imm-offset) -> VGPR-pipelined, no SGPR bottleneck.
// W streamed per-lane float4 with 1-deep prefetch. Stores: 64 consecutive
// dwords per (wave, b) into pos-space res (full cache lines).
__launch_bounds__(256, 4)
__global__ void main_k(const float* __restrict__ OT, const float* __restrict__ W,
                       const int* __restrict__ sorted, const int4* __restrict__ desc,
                       const int* __restrict__ ntot, float* __restrict__ res) {
    const int nt = *ntot;
    const int bid = blockIdx.x;
    const int ci = bid >> 2;
    if (ci >= nt) return;
    const int hq = bid & 3;
    const int4 d = desc[ci];
    const int q     = __builtin_amdgcn_readfirstlane(d.x);
    const int start = __builtin_amdgcn_readfirstlane(d.y);
    const int len   = __builtin_amdgcn_readfirstlane(d.z);
    const int tid = threadIdx.x;
    const int lane = tid & 63;
    const int w = __builtin_amdgcn_readfirstlane(tid >> 6);

    __shared__ float OTt[BB * HQ];  // 24 KB

    // stage OT[0..31][hq*192 .. +192) -> LDS (each thread: 6 float4)
    {
        const int r = tid >> 3;        // 0..31 (b)
        const int cg = tid & 7;        // col group
        const float* src = OT + ((size_t)r * QQ + q) * HH + hq * HQ;
#pragma unroll
        for (int k = 0; k < 6; ++k) {
            const int c4 = cg + 8 * k;  // 0..47
            *(float4*)&OTt[r * HQ + 4 * c4] = *(const float4*)(src + 4 * c4);
        }
    }

    const int v = sorted[start + min(lane, len - 1)];
    const float* wp = W + (size_t)v * HH + hq * HQ;

    __syncthreads();

    float acc[8] = {0.f, 0.f, 0.f, 0.f, 0.f, 0.f, 0.f, 0.f};
    float4 wr = *(const float4*)(wp);

#pragma unroll 2
    for (int t = 0; t < HQ / 4; ++t) {
        const float4 wcur = wr;
        if (t + 1 < HQ / 4) wr = *(const float4*)(wp + 4 * (t + 1));
#pragma unroll
        for (int j = 0; j < 8; ++j) {
            const float4 o = *(const float4*)&OTt[(8 * w + j) * HQ + 4 * t];
            float a = acc[j];
            a = fmaf(wcur.x, o.x, a);
            a = fmaf(wcur.y, o.y, a);
            a = fmaf(wcur.z, o.z, a);
            a = fmaf(wcur.w, o.w, a);
            acc[j] = a;
        }
    }

    if (lane < len) {
        float* rp = res + (size_t)(hq * BB + 8 * w) * SB + start + lane;
#pragma unroll
        for (int j = 0; j < 8; ++j)
            rp[(size_t)j * SB] = acc[j];
    }
}

// ---------- combine in pos-space: all reads coalesced ----------
__global__ void combine_k(const float* __restrict__ res, const int* __restrict__ sorted,
                          const float* __restrict__ bias, float* __restrict__ out) {
    const int pos = blockIdx.x * 256 + threadIdx.x;
    if (pos >= VV) return;
    const int b = blockIdx.y;
    float s = res[(size_t)b * SB + pos]
            + res[(size_t)(BB + b) * SB + pos]
            + res[(size_t)(2 * BB + b) * SB + pos]
            + res[(size_t)(3 * BB + b) * SB + pos];
    const int v = sorted[pos];
    out[(size_t)b * VV + v] = s + bias[v];
}

extern "C" void kernel_launch(void* const* d_in, const int* in_sizes, int n_in,
                              void* d_out, int out_size, void* d_ws, size_t ws_size,
                              hipStream_t stream) {
    const float* OT   = (const float*)d_in[0];  // [B,Q,H]
    const float* W    = (const float*)d_in[1];  // [V,H]
    const float* bias = (const float*)d_in[2];  // [V]
    const int*   pid  = (const int*)d_in[3];    // [V]
    float* out = (float*)d_out;                 // [B,V]

    char* ws = (char*)d_ws;
    int*   ntot   = (int*)(ws + WS_NTOT);
    int*   sorted = (int*)(ws + WS_SORTED);
    int4*  desc   = (int4*)(ws + WS_DESC);
    float* res    = (float*)(ws + WS_RES);

    prep_k<<<1, 1024, 0, stream>>>(pid, sorted, desc, ntot);

    main_k<<<4 * MAXDESC, 256, 0, stream>>>(OT, W, sorted, desc, ntot, res);

    combine_k<<<dim3((VV + 255) / 256, BB), 256, 0, stream>>>(res, sorted, bias, out);
}

// Round 6
// 54.130 us; speedup vs baseline: 2.9720x; 1.4059x over previous
//
#include <hip/hip_runtime.h>
#include <hip/hip_bf16.h>

// out[b,v] = dot(OT[b, pid[v], :], W[v, :]) + bias[v]
// B=32, Q=180, H=768, V=19004. fp32 in/out, bf16 MFMA inside.
#define BB 32
#define QQ 180
#define HH 768
#define VV 19004
#define VB 64
#define KH 384       // K per half
#define SB 19008     // res stride (pos dim)
#define MAXDESC 480
#define STRIDE 392   // OT LDS row stride in bf16 elems (384 + 8 pad = 784 B)

// ws layout (bytes)
#define WS_CNT    0        // 256 ints
#define WS_CUR    1024     // 256 ints
#define WS_NTOT   2048     // 1 int
#define WS_SORTED 4096     // VV ints
#define WS_DESC   81920    // 480 int4
#define WS_RES    90112    // 2 * 32 * 19008 * 4 = 4,866,048 B

typedef __attribute__((ext_vector_type(8))) short short8v;  // 8 bf16 (4 VGPR)
typedef __attribute__((ext_vector_type(4))) float f32x4;

__device__ __forceinline__ short f2bf(float f) {  // RNE fp32->bf16
    unsigned u = __builtin_bit_cast(unsigned, f);
    u += 0x7FFFu + ((u >> 16) & 1u);
    return (short)(u >> 16);
}

// ---------- pre-pass ----------
__global__ void count_k(const int* __restrict__ pid, int* __restrict__ cnt) {
    __shared__ int lc[QQ];
    for (int i = threadIdx.x; i < QQ; i += blockDim.x) lc[i] = 0;
    __syncthreads();
    for (int v = blockIdx.x * blockDim.x + threadIdx.x; v < VV;
         v += gridDim.x * blockDim.x)
        atomicAdd(&lc[pid[v]], 1);
    __syncthreads();
    for (int i = threadIdx.x; i < QQ; i += blockDim.x) {
        int c = lc[i];
        if (c) atomicAdd(&cnt[i], c);
    }
}

__global__ void scan_desc_k(const int* __restrict__ cnt, int* __restrict__ cursor,
                            int4* __restrict__ desc, int* __restrict__ ntot) {
    __shared__ int sc[256];
    __shared__ int sn[256];
    const int t = threadIdx.x;
    const int c = (t < QQ) ? cnt[t] : 0;
    sc[t] = c;
    __syncthreads();
    for (int off = 1; off < 256; off <<= 1) {
        int add = (t >= off) ? sc[t - off] : 0;
        __syncthreads();
        sc[t] += add;
        __syncthreads();
    }
    const int qstart = sc[t] - c;
    if (t < QQ) cursor[t] = qstart;
    const int nch = (c + VB - 1) / VB;
    sn[t] = nch;
    __syncthreads();
    for (int off = 1; off < 256; off <<= 1) {
        int add = (t >= off) ? sn[t - off] : 0;
        __syncthreads();
        sn[t] += add;
        __syncthreads();
    }
    const int cb = sn[t] - nch;
    if (t < QQ) {
        for (int j = 0; j < nch; ++j)
            desc[cb + j] = make_int4(t, qstart + j * VB, min(VB, c - j * VB), 0);
    }
    if (t == 255) *ntot = sn[255];
}

__global__ void scatter_k(const int* __restrict__ pid, int* __restrict__ cursor,
                          int* __restrict__ sorted) {
    for (int v = blockIdx.x * blockDim.x + threadIdx.x; v < VV;
         v += gridDim.x * blockDim.x) {
        int q = pid[v];
        int pos = atomicAdd(&cursor[q], 1);
        sorted[pos] = v;
    }
}

// ---------- main: MFMA 16x16x32 bf16, block = (chunk, K-half) ----------
// A = OT (M=b), B = W (N=v) so C cols = consecutive v -> coalesced stores.
// 4 waves; wave w owns v-tile w (16 v's), both b-tiles, K=384 (12 steps x2 MFMA).
// OT half staged once in LDS as bf16 (25 KB); W streamed per-lane, cvt in-reg.
__launch_bounds__(256)
__global__ void main_k(const float* __restrict__ OT, const float* __restrict__ W,
                       const int* __restrict__ sorted, const int4* __restrict__ desc,
                       const int* __restrict__ ntot, float* __restrict__ res) {
    const int nt = *ntot;
    const int bid = blockIdx.x;
    const int ci = bid >> 1;
    if (ci >= nt) return;
    const int kh = bid & 1;
    const int4 d = desc[ci];
    const int q     = __builtin_amdgcn_readfirstlane(d.x);
    const int start = __builtin_amdgcn_readfirstlane(d.y);
    const int len   = __builtin_amdgcn_readfirstlane(d.z);
    const int tid = threadIdx.x;

    __shared__ short OTlds[BB * STRIDE];  // 25,088 B

    // stage OT[0..31][q][kh*384 .. +384) as bf16 (coalesced fp32 reads)
    {
        const int r = tid >> 3;   // b row 0..31
        const int o = tid & 7;    // octet
        const float* src = OT + ((size_t)r * QQ + q) * HH + kh * KH + o * 8;
        short* dst = &OTlds[r * STRIDE + o * 8];
#pragma unroll
        for (int it = 0; it < 6; ++it) {
            const float4 f0 = *(const float4*)(src + it * 64);
            const float4 f1 = *(const float4*)(src + it * 64 + 4);
            short8v s;
            s[0] = f2bf(f0.x); s[1] = f2bf(f0.y); s[2] = f2bf(f0.z); s[3] = f2bf(f0.w);
            s[4] = f2bf(f1.x); s[5] = f2bf(f1.y); s[6] = f2bf(f1.z); s[7] = f2bf(f1.w);
            *(short8v*)(dst + it * 64) = s;
        }
    }

    const int lane = tid & 63;
    const int w = tid >> 6;           // v-tile
    const int co = lane & 15;         // frag col
    const int kq = lane >> 4;         // k-quad
    const int vl = 16 * w + co;       // v-local in chunk
    const int vg = sorted[start + min(vl, len - 1)];
    const float* wp = W + (size_t)vg * HH + kh * KH + kq * 8;
    const short* a0 = &OTlds[co * STRIDE + kq * 8];

    __syncthreads();

    f32x4 acc0 = {0.f, 0.f, 0.f, 0.f};
    f32x4 acc1 = {0.f, 0.f, 0.f, 0.f};
#pragma unroll 3
    for (int kk = 0; kk < 12; ++kk) {
        const float4 wf0 = *(const float4*)(wp + kk * 32);
        const float4 wf1 = *(const float4*)(wp + kk * 32 + 4);
        short8v bf;
        bf[0] = f2bf(wf0.x); bf[1] = f2bf(wf0.y); bf[2] = f2bf(wf0.z); bf[3] = f2bf(wf0.w);
        bf[4] = f2bf(wf1.x); bf[5] = f2bf(wf1.y); bf[6] = f2bf(wf1.z); bf[7] = f2bf(wf1.w);
        const short8v a0v = *(const short8v*)(a0 + kk * 32);
        const short8v a1v = *(const short8v*)(a0 + 16 * STRIDE + kk * 32);
        acc0 = __builtin_amdgcn_mfma_f32_16x16x32_bf16(a0v, bf, acc0, 0, 0, 0);
        acc1 = __builtin_amdgcn_mfma_f32_16x16x32_bf16(a1v, bf, acc1, 0, 0, 0);
    }

    // C[row=b][col=v]: row = (lane>>4)*4 + reg, col = lane&15  (m89-verified)
    if (vl < len) {
        float* rp = res + (size_t)(kh * BB) * SB + start + vl;
#pragma unroll
        for (int r2 = 0; r2 < 4; ++r2) {
            rp[(size_t)(kq * 4 + r2) * SB]      = acc0[r2];
            rp[(size_t)(16 + kq * 4 + r2) * SB] = acc1[r2];
        }
    }
}

// ---------- combine two K-halves in pos-space ----------
__global__ void combine_k(const float* __restrict__ res, const int* __restrict__ sorted,
                          const float* __restrict__ bias, float* __restrict__ out) {
    const int pos = blockIdx.x * 256 + threadIdx.x;
    if (pos >= VV) return;
    const int b = blockIdx.y;
    const float s = res[(size_t)b * SB + pos] + res[(size_t)(BB + b) * SB + pos];
    const int v = sorted[pos];
    out[(size_t)b * VV + v] = s + bias[v];
}

extern "C" void kernel_launch(void* const* d_in, const int* in_sizes, int n_in,
                              void* d_out, int out_size, void* d_ws, size_t ws_size,
                              hipStream_t stream) {
    const float* OT   = (const float*)d_in[0];  // [B,Q,H]
    const float* W    = (const float*)d_in[1];  // [V,H]
    const float* bias = (const float*)d_in[2];  // [V]
    const int*   pid  = (const int*)d_in[3];    // [V]
    float* out = (float*)d_out;                 // [B,V]

    char* ws = (char*)d_ws;
    int*   cnt    = (int*)(ws + WS_CNT);
    int*   cursor = (int*)(ws + WS_CUR);
    int*   ntot   = (int*)(ws + WS_NTOT);
    int*   sorted = (int*)(ws + WS_SORTED);
    int4*  desc   = (int4*)(ws + WS_DESC);
    float* res    = (float*)(ws + WS_RES);

    hipMemsetAsync(cnt, 0, 256 * sizeof(int), stream);
    count_k<<<80, 256, 0, stream>>>(pid, cnt);
    scan_desc_k<<<1, 256, 0, stream>>>(cnt, cursor, desc, ntot);
    scatter_k<<<80, 256, 0, stream>>>(pid, cursor, sorted);

    main_k<<<2 * MAXDESC, 256, 0, stream>>>(OT, W, sorted, desc, ntot, res);

    combine_k<<<dim3((VV + 255) / 256, BB), 256, 0, stream>>>(res, sorted, bias, out);
}

// Round 7
// 49.257 us; speedup vs baseline: 3.2660x; 1.0989x over previous
//
#include <hip/hip_runtime.h>
#include <hip/hip_bf16.h>

// out[b,v] = dot(OT[b, pid[v], :], W[v, :]) + bias[v]
// B=32, Q=180, H=768, V=19004. fp32 in/out, bf16 MFMA inside.
#define BB 32
#define QQ 180
#define HH 768
#define VV 19004
#define VB 64
#define KH 384       // K per half
#define SB 19008     // res stride (pos dim)
#define MAXDESC 480
#define STRIDE 392   // OT LDS row stride in bf16 elems (384 + 8 pad = 784 B)

// ws layout (bytes)
#define WS_NTOT   2048     // 1 int
#define WS_SORTED 4096     // VV ints
#define WS_DESC   81920    // 480 int4
#define WS_RES    90112    // 2 * 32 * 19008 * 4 = 4,866,048 B

typedef __attribute__((ext_vector_type(8))) short short8v;  // 8 bf16 (4 VGPR)
typedef __attribute__((ext_vector_type(4))) float f32x4;

__device__ __forceinline__ short f2bf(float f) {  // RNE fp32->bf16
    unsigned u = __builtin_bit_cast(unsigned, f);
    u += 0x7FFFu + ((u >> 16) & 1u);
    return (short)(u >> 16);
}

// ---------- fused pre-pass: histogram + scan + desc + scatter, 1 block ----------
__global__ void prep_k(const int* __restrict__ pid, int* __restrict__ sorted,
                       int4* __restrict__ desc, int* __restrict__ ntot) {
    __shared__ int cnt[256];
    __shared__ int sc[256];
    __shared__ int sn[256];
    __shared__ int cur[256];
    const int t = threadIdx.x;  // 1024 threads
    if (t < 256) cnt[t] = 0;
    __syncthreads();
    for (int v = t; v < VV; v += 1024) atomicAdd(&cnt[pid[v]], 1);
    __syncthreads();
    if (t < 256) sc[t] = cnt[t];
    __syncthreads();
    for (int off = 1; off < 256; off <<= 1) {
        int add = (t < 256 && t >= off) ? sc[t - off] : 0;
        __syncthreads();
        if (t < 256) sc[t] += add;
        __syncthreads();
    }
    if (t < 256) {
        const int c = cnt[t];
        cur[t] = sc[t] - c;                      // q start
        sn[t] = (c + VB - 1) / VB;               // chunks for this q
    }
    __syncthreads();
    for (int off = 1; off < 256; off <<= 1) {
        int add = (t < 256 && t >= off) ? sn[t - off] : 0;
        __syncthreads();
        if (t < 256) sn[t] += add;
        __syncthreads();
    }
    if (t < QQ) {
        const int c = cnt[t];
        const int nch = (c + VB - 1) / VB;
        const int cb = sn[t] - nch;
        const int qs = cur[t];
        for (int j = 0; j < nch; ++j)
            desc[cb + j] = make_int4(t, qs + j * VB, min(VB, c - j * VB), 0);
    }
    if (t == 255) *ntot = sn[255];
    __syncthreads();
    for (int v = t; v < VV; v += 1024) {
        const int q = pid[v];
        const int pos = atomicAdd(&cur[q], 1);   // LDS atomic: fast
        sorted[pos] = v;
    }
}

// ---------- main: MFMA 16x16x32 bf16, block = (chunk, K-half) ----------
// A = OT (M=b), B = W (N=v) so C cols = consecutive v -> coalesced stores.
// 4 waves; wave w owns v-tile w (16 v's), both b-tiles, K=384 (12 steps x2 MFMA).
// OT half staged once in LDS as bf16 (25 KB); W burst-loaded: ALL 24 float4
// loads issued before the compute loop (24-deep MLP per lane) -> latency
// becomes throughput. Stores: full-line pos-space res.
__launch_bounds__(256)
__global__ void main_k(const float* __restrict__ OT, const float* __restrict__ W,
                       const int* __restrict__ sorted, const int4* __restrict__ desc,
                       const int* __restrict__ ntot, float* __restrict__ res) {
    const int nt = *ntot;
    const int bid = blockIdx.x;
    const int ci = bid >> 1;
    if (ci >= nt) return;
    const int kh = bid & 1;
    const int4 d = desc[ci];
    const int q     = __builtin_amdgcn_readfirstlane(d.x);
    const int start = __builtin_amdgcn_readfirstlane(d.y);
    const int len   = __builtin_amdgcn_readfirstlane(d.z);
    const int tid = threadIdx.x;

    __shared__ short OTlds[BB * STRIDE];  // 25,088 B

    // stage OT[0..31][q][kh*384 .. +384) as bf16 (coalesced fp32 reads)
    {
        const int r = tid >> 3;   // b row 0..31
        const int o = tid & 7;    // octet
        const float* src = OT + ((size_t)r * QQ + q) * HH + kh * KH + o * 8;
        short* dst = &OTlds[r * STRIDE + o * 8];
#pragma unroll
        for (int it = 0; it < 6; ++it) {
            const float4 f0 = *(const float4*)(src + it * 64);
            const float4 f1 = *(const float4*)(src + it * 64 + 4);
            short8v s;
            s[0] = f2bf(f0.x); s[1] = f2bf(f0.y); s[2] = f2bf(f0.z); s[3] = f2bf(f0.w);
            s[4] = f2bf(f1.x); s[5] = f2bf(f1.y); s[6] = f2bf(f1.z); s[7] = f2bf(f1.w);
            *(short8v*)(dst + it * 64) = s;
        }
    }

    const int lane = tid & 63;
    const int w = tid >> 6;           // v-tile
    const int co = lane & 15;         // frag col
    const int kq = lane >> 4;         // k-quad
    const int vl = 16 * w + co;       // v-local in chunk
    const int vg = sorted[start + min(vl, len - 1)];
    const float4* wp4 = (const float4*)(W + (size_t)vg * HH + kh * KH + kq * 8);
    const short* a0 = &OTlds[co * STRIDE + kq * 8];

    // burst: issue ALL W loads before any use (24 outstanding 16B/lane)
    float4 wf[24];
#pragma unroll
    for (int kk = 0; kk < 12; ++kk) {
        wf[2 * kk]     = wp4[kk * 8];
        wf[2 * kk + 1] = wp4[kk * 8 + 1];
    }

    __syncthreads();

    f32x4 acc0 = {0.f, 0.f, 0.f, 0.f};
    f32x4 acc1 = {0.f, 0.f, 0.f, 0.f};
#pragma unroll
    for (int kk = 0; kk < 12; ++kk) {
        const float4 wf0 = wf[2 * kk];
        const float4 wf1 = wf[2 * kk + 1];
        short8v bf;
        bf[0] = f2bf(wf0.x); bf[1] = f2bf(wf0.y); bf[2] = f2bf(wf0.z); bf[3] = f2bf(wf0.w);
        bf[4] = f2bf(wf1.x); bf[5] = f2bf(wf1.y); bf[6] = f2bf(wf1.z); bf[7] = f2bf(wf1.w);
        const short8v a0v = *(const short8v*)(a0 + kk * 32);
        const short8v a1v = *(const short8v*)(a0 + 16 * STRIDE + kk * 32);
        acc0 = __builtin_amdgcn_mfma_f32_16x16x32_bf16(a0v, bf, acc0, 0, 0, 0);
        acc1 = __builtin_amdgcn_mfma_f32_16x16x32_bf16(a1v, bf, acc1, 0, 0, 0);
    }

    // C[row=b][col=v]: row = (lane>>4)*4 + reg, col = lane&15  (m89-verified)
    if (vl < len) {
        float* rp = res + (size_t)(kh * BB) * SB + start + vl;
#pragma unroll
        for (int r2 = 0; r2 < 4; ++r2) {
            rp[(size_t)(kq * 4 + r2) * SB]      = acc0[r2];
            rp[(size_t)(16 + kq * 4 + r2) * SB] = acc1[r2];
        }
    }
}

// ---------- combine two K-halves in pos-space ----------
__global__ void combine_k(const float* __restrict__ res, const int* __restrict__ sorted,
                          const float* __restrict__ bias, float* __restrict__ out) {
    const int pos = blockIdx.x * 256 + threadIdx.x;
    if (pos >= VV) return;
    const int b = blockIdx.y;
    const float s = res[(size_t)b * SB + pos] + res[(size_t)(BB + b) * SB + pos];
    const int v = sorted[pos];
    out[(size_t)b * VV + v] = s + bias[v];
}

extern "C" void kernel_launch(void* const* d_in, const int* in_sizes, int n_in,
                              void* d_out, int out_size, void* d_ws, size_t ws_size,
                              hipStream_t stream) {
    const float* OT   = (const float*)d_in[0];  // [B,Q,H]
    const float* W    = (const float*)d_in[1];  // [V,H]
    const float* bias = (const float*)d_in[2];  // [V]
    const int*   pid  = (const int*)d_in[3];    // [V]
    float* out = (float*)d_out;                 // [B,V]

    char* ws = (char*)d_ws;
    int*   ntot   = (int*)(ws + WS_NTOT);
    int*   sorted = (int*)(ws + WS_SORTED);
    int4*  desc   = (int4*)(ws + WS_DESC);
    float* res    = (float*)(ws + WS_RES);

    prep_k<<<1, 1024, 0, stream>>>(pid, sorted, desc, ntot);

    main_k<<<2 * MAXDESC, 256, 0, stream>>>(OT, W, sorted, desc, ntot, res);

    combine_k<<<dim3((VV + 255) / 256, BB), 256, 0, stream>>>(res, sorted, bias, out);
}